// Round 1
// baseline (4080.090 us; speedup 1.0000x reference)
//
#include <hip/hip_runtime.h>
#include <math.h>

#define BATCH 8
#define SEQ 384
#define DIM 768
#define NH 12
#define DH 64
#define NPOS 767
#define POS_OFF 128
#define IBLK 32

// ---------------- fp32 tiled GEMM: C[M,N] = A[M,K] @ W[K,N] (+b1 +b2) ------
// 64x64 tile, Ktile=16, 256 threads, 4x4 per thread.
__global__ __launch_bounds__(256) void gemm_f32(
    const float* __restrict__ A, const float* __restrict__ W,
    const float* __restrict__ b1, const float* __restrict__ b2,
    float* __restrict__ C, int M, int N, int K)
{
    __shared__ float As[16][65];   // [kk][m], padded
    __shared__ float Ws[16][64];   // [kk][n]
    const int tid = threadIdx.x;
    const int tx = tid & 15, ty = tid >> 4;
    const int m0 = blockIdx.y * 64, n0 = blockIdx.x * 64;
    float acc[4][4] = {};
    for (int k0 = 0; k0 < K; k0 += 16) {
        for (int e = tid; e < 64 * 16; e += 256) {
            int m = e >> 4, kk = e & 15;
            float val = 0.f;
            if (m0 + m < M) val = A[(size_t)(m0 + m) * K + k0 + kk];
            As[kk][m] = val;
        }
        for (int e = tid; e < 64 * 16; e += 256) {
            int kk = e >> 6, n = e & 63;
            Ws[kk][n] = W[(size_t)(k0 + kk) * N + n0 + n];
        }
        __syncthreads();
#pragma unroll
        for (int kk = 0; kk < 16; ++kk) {
            float a[4], w[4];
#pragma unroll
            for (int i = 0; i < 4; ++i) a[i] = As[kk][ty * 4 + i];
#pragma unroll
            for (int j = 0; j < 4; ++j) w[j] = Ws[kk][tx * 4 + j];
#pragma unroll
            for (int i = 0; i < 4; ++i)
#pragma unroll
                for (int j = 0; j < 4; ++j)
                    acc[i][j] += a[i] * w[j];
        }
        __syncthreads();
    }
    for (int i = 0; i < 4; ++i) {
        int m = m0 + ty * 4 + i;
        if (m >= M) continue;
        for (int j = 0; j < 4; ++j) {
            int n = n0 + tx * 4 + j;
            float bias = (b1 ? b1[n] : 0.f) + (b2 ? b2[n] : 0.f);
            C[(size_t)m * N + n] = acc[i][j] + bias;
        }
    }
}

// ---------------- fused disentangled attention ----------------------------
// grid: (SEQ/IBLK, NH, BATCH), 256 threads.
// scores[i,j] = (q[i]·k[j] + q[i]·KpD[j-i+383] + QpD[j-i+383]·k[j]) * 0.125
__global__ __launch_bounds__(256) void attn_f32(
    const float* __restrict__ q, const float* __restrict__ k,
    const float* __restrict__ v, const float* __restrict__ Kp,
    const float* __restrict__ Qp, float* __restrict__ o)
{
    __shared__ float qs[IBLK][DH + 1];     // 8.1 KB
    __shared__ float ks[64][DH + 1];       // 16.6 KB (reused for v tiles)
    __shared__ float kps[95][DH + 1];      // 24.7 KB
    __shared__ float qps[95][DH + 1];      // 24.7 KB
    __shared__ float sc[IBLK][SEQ + 1];    // 49.3 KB
    __shared__ float red[IBLK][8];
    __shared__ float rmax[IBLK], rsum[IBLK];

    const int tid = threadIdx.x;
    const int i0 = blockIdx.x * IBLK;
    const int h = blockIdx.y;
    const int b = blockIdx.z;
    const float* qb = q + (size_t)b * SEQ * DIM + h * DH;
    const float* kb = k + (size_t)b * SEQ * DIM + h * DH;
    const float* vb = v + (size_t)b * SEQ * DIM + h * DH;

    for (int e = tid; e < IBLK * DH; e += 256) {
        int i = e >> 6, d = e & 63;
        qs[i][d] = qb[(size_t)(i0 + i) * DIM + d];
    }

    const int ti = tid & 31;       // score-phase row
    const int jslot = tid >> 5;    // 0..7

    for (int j0 = 0; j0 < SEQ; j0 += 64) {
        for (int e = tid; e < 64 * DH; e += 256) {
            int j = e >> 6, d = e & 63;
            ks[j][d] = kb[(size_t)(j0 + j) * DIM + d];
        }
        const int tbase = j0 - i0 + 352;   // 95 band rows, always in [0,767)
        for (int e = tid; e < 95 * DH; e += 256) {
            int t = e >> 6, d = e & 63;
            kps[t][d] = Kp[(size_t)(tbase + t) * DIM + h * DH + d];
            qps[t][d] = Qp[(size_t)(tbase + t) * DIM + h * DH + d];
        }
        __syncthreads();
        for (int jj = 0; jj < 8; ++jj) {
            int jl = jslot + 8 * jj;
            int tl = jl - ti + 31;         // 0..94
            float s = 0.f;
#pragma unroll 8
            for (int d = 0; d < DH; ++d) {
                s += qs[ti][d] * (ks[jl][d] + kps[tl][d]) + qps[tl][d] * ks[jl][d];
            }
            sc[ti][j0 + jl] = s * 0.125f;
        }
        __syncthreads();
    }

    // two-pass softmax over 384 cols (unnormalized exp; divide at PV write)
    {
        float m = -1e30f;
        for (int j = jslot * 48; j < jslot * 48 + 48; ++j)
            m = fmaxf(m, sc[ti][j]);
        red[ti][jslot] = m;
    }
    __syncthreads();
    if (tid < IBLK) {
        float m = red[tid][0];
        for (int c = 1; c < 8; ++c) m = fmaxf(m, red[tid][c]);
        rmax[tid] = m;
    }
    __syncthreads();
    {
        float m = rmax[ti];
        float sum = 0.f;
        for (int j = jslot * 48; j < jslot * 48 + 48; ++j) {
            float e = __expf(sc[ti][j] - m);
            sc[ti][j] = e;
            sum += e;
        }
        red[ti][jslot] = sum;
    }
    __syncthreads();
    if (tid < IBLK) {
        float sum = 0.f;
        for (int c = 0; c < 8; ++c) sum += red[tid][c];
        rsum[tid] = sum;
    }
    __syncthreads();

    // PV: remap threads so stores coalesce: (row ti2, 8-wide d slot)
    const int ti2 = tid >> 3;      // 0..31
    const int dslot = tid & 7;     // 0..7
    float acc[8] = {};
    for (int j0 = 0; j0 < SEQ; j0 += 64) {
        __syncthreads();
        for (int e = tid; e < 64 * DH; e += 256) {
            int j = e >> 6, d = e & 63;
            ks[j][d] = vb[(size_t)(j0 + j) * DIM + d];
        }
        __syncthreads();
        for (int jl = 0; jl < 64; ++jl) {
            float w = sc[ti2][j0 + jl];
#pragma unroll
            for (int dd = 0; dd < 8; ++dd)
                acc[dd] += w * ks[jl][dslot * 8 + dd];
        }
    }
    float inv = 1.f / rsum[ti2];
    float* orow = o + (size_t)b * SEQ * DIM + (size_t)(i0 + ti2) * DIM + h * DH + dslot * 8;
#pragma unroll
    for (int dd = 0; dd < 8; ++dd)
        orow[dd] = acc[dd] * inv;
}

extern "C" void kernel_launch(void* const* d_in, const int* in_sizes, int n_in,
                              void* d_out, int out_size, void* d_ws, size_t ws_size,
                              hipStream_t stream) {
    const float* x   = (const float*)d_in[0];
    const float* rpe = (const float*)d_in[1];
    const float* Wq  = (const float*)d_in[2];
    const float* bq  = (const float*)d_in[3];
    const float* Wk  = (const float*)d_in[4];
    const float* bk  = (const float*)d_in[5];
    const float* Wv  = (const float*)d_in[6];
    const float* bv  = (const float*)d_in[7];
    const float* qbias = (const float*)d_in[8];
    const float* vbias = (const float*)d_in[9];
    const float* Wpk = (const float*)d_in[10];
    const float* Wpq = (const float*)d_in[11];
    const float* Wo  = (const float*)d_in[12];
    const float* bo  = (const float*)d_in[13];
    float* out = (float*)d_out;

    const size_t NTOK = (size_t)BATCH * SEQ;        // 3072
    float* ws = (float*)d_ws;
    float* qw  = ws;                                 // 3072*768
    float* kw  = qw + NTOK * DIM;
    float* vw  = kw + NTOK * DIM;
    float* ao  = vw + NTOK * DIM;
    float* KpD = ao + NTOK * DIM;                    // 767*768
    float* QpD = KpD + (size_t)NPOS * DIM;

    dim3 blk(256);
    dim3 gproj(DIM / 64, NTOK / 64);                 // (12, 48)
    dim3 gpos(DIM / 64, (NPOS + 63) / 64);           // (12, 12)

    gemm_f32<<<gproj, blk, 0, stream>>>(x, Wq, bq, qbias, qw, NTOK, DIM, DIM);
    gemm_f32<<<gproj, blk, 0, stream>>>(x, Wk, bk, nullptr, kw, NTOK, DIM, DIM);
    gemm_f32<<<gproj, blk, 0, stream>>>(x, Wv, bv, vbias, vw, NTOK, DIM, DIM);
    gemm_f32<<<gpos, blk, 0, stream>>>(rpe + (size_t)POS_OFF * DIM, Wpk, nullptr, nullptr, KpD, NPOS, DIM, DIM);
    gemm_f32<<<gpos, blk, 0, stream>>>(rpe + (size_t)POS_OFF * DIM, Wpq, nullptr, nullptr, QpD, NPOS, DIM, DIM);

    dim3 gattn(SEQ / IBLK, NH, BATCH);               // (12, 12, 8)
    attn_f32<<<gattn, blk, 0, stream>>>(qw, kw, vw, KpD, QpD, ao);

    gemm_f32<<<gproj, blk, 0, stream>>>(ao, Wo, bo, nullptr, out, NTOK, DIM, DIM);
}

// Round 2
// 292.815 us; speedup vs baseline: 13.9340x; 13.9340x over previous
//
#include <hip/hip_runtime.h>
#include <hip/hip_bf16.h>
#include <math.h>

#define BATCH 8
#define SEQ 384
#define DIM 768
#define NH 12
#define DH 64
#define NPOS 767
#define POS_OFF 128
#define NTOK (BATCH * SEQ)

typedef __attribute__((ext_vector_type(8))) short short8;
typedef __attribute__((ext_vector_type(4))) float floatx4;

__device__ __forceinline__ ushort f2bf(float f) {
    __hip_bfloat16 h = __float2bfloat16(f);
    return *reinterpret_cast<ushort*>(&h);
}

// ---------- convert fp32 -> bf16, row-major, n multiple of 4 --------------
__global__ void cvt_rows(const float* __restrict__ in, ushort* __restrict__ out, int n4) {
    int idx = blockIdx.x * blockDim.x + threadIdx.x;
    if (idx >= n4) return;
    float4 f = ((const float4*)in)[idx];
    ushort o[4] = {f2bf(f.x), f2bf(f.y), f2bf(f.z), f2bf(f.w)};
    *(uint2*)&out[(size_t)idx * 4] = *(uint2*)o;
}

// ---------- convert + transpose 768x768: out[n][k] = bf16(in[k][n]) -------
__global__ __launch_bounds__(256) void cvt_transpose(const float* __restrict__ in, ushort* __restrict__ out) {
    __shared__ float t[64][65];
    const int tid = threadIdx.x;
    const int r0 = blockIdx.y * 64, c0 = blockIdx.x * 64;
    for (int p = 0; p < 16; ++p) {
        int e = tid + p * 256, i = e >> 6, j = e & 63;
        t[i][j] = in[(size_t)(r0 + i) * DIM + c0 + j];
    }
    __syncthreads();
    for (int p = 0; p < 16; ++p) {
        int e = tid + p * 256, i = e >> 6, j = e & 63;
        out[(size_t)(c0 + i) * DIM + r0 + j] = f2bf(t[j][i]);
    }
}

// ---------- bf16 MFMA GEMM: C[M,N] = A[M,K] @ Bt[N,K]^T (+b1+b2) ----------
// 64x64 tile, 256 threads (4 waves), K multiple of 64, N multiple of 64.
__global__ __launch_bounds__(256) void gemm_bf16(
    const ushort* __restrict__ A, const ushort* __restrict__ Bt,
    const float* __restrict__ b1, const float* __restrict__ b2,
    float* __restrict__ outF, ushort* __restrict__ outB,
    int M, int N, int K)
{
    __shared__ ushort As[64][72];
    __shared__ ushort Bs[64][72];
    const int tid = threadIdx.x;
    const int lane = tid & 63, wave = tid >> 6;
    const int m0 = blockIdx.y * 64, n0 = blockIdx.x * 64;
    floatx4 acc[4] = {};
    for (int k0 = 0; k0 < K; k0 += 64) {
        for (int p = 0; p < 2; ++p) {
            int e = tid + p * 256;
            int m = e >> 3, k8 = e & 7;
            uint4 val = {0, 0, 0, 0};
            if (m0 + m < M) val = *(const uint4*)(A + (size_t)(m0 + m) * K + k0 + k8 * 8);
            *(uint4*)&As[m][k8 * 8] = val;
            uint4 bval = *(const uint4*)(Bt + (size_t)(n0 + m) * K + k0 + k8 * 8);
            *(uint4*)&Bs[m][k8 * 8] = bval;
        }
        __syncthreads();
#pragma unroll
        for (int kk = 0; kk < 64; kk += 32) {
            short8 a = *(const short8*)&As[wave * 16 + (lane & 15)][kk + (lane >> 4) * 8];
#pragma unroll
            for (int c = 0; c < 4; ++c) {
                short8 b = *(const short8*)&Bs[c * 16 + (lane & 15)][kk + (lane >> 4) * 8];
                acc[c] = __builtin_amdgcn_mfma_f32_16x16x32_bf16(a, b, acc[c], 0, 0, 0);
            }
        }
        __syncthreads();
    }
#pragma unroll
    for (int c = 0; c < 4; ++c) {
        int col = n0 + c * 16 + (lane & 15);
        float bias = (b1 ? b1[col] : 0.f) + (b2 ? b2[col] : 0.f);
#pragma unroll
        for (int r = 0; r < 4; ++r) {
            int row = m0 + wave * 16 + (lane >> 4) * 4 + r;
            if (row >= M) continue;
            float v = acc[c][r] + bias;
            if (outF) outF[(size_t)row * N + col] = v;
            if (outB) outB[(size_t)row * N + col] = f2bf(v);
        }
    }
}

// ---------- score kernel: scores = (c2c + c2p + p2c) * 0.125 --------------
// grid (S/64, NH, BATCH), 512 threads (8 waves). Band trick per j-tile.
__global__ __launch_bounds__(512) void score_kernel(
    const ushort* __restrict__ qb, const ushort* __restrict__ kb,
    const ushort* __restrict__ Kpb, const ushort* __restrict__ Qpb,
    float* __restrict__ scores)
{
    __shared__ ushort qs[64][72];
    __shared__ ushort kt[64][72];
    __shared__ ushort kps[128][72];
    __shared__ ushort qps[128][72];
    __shared__ float dq[64][132];
    __shared__ float dk[128][65];
    __shared__ float cc[64][68];

    const int tid = threadIdx.x;
    const int lane = tid & 63, wave = tid >> 6;
    const int i0 = blockIdx.x * 64;
    const int h = blockIdx.y;
    const int b = blockIdx.z;

    // stage q block (once)
    {
        int i = tid >> 3, k8 = tid & 7;
        uint4 v = *(const uint4*)(qb + ((size_t)(b * SEQ + i0 + i) * DIM) + h * DH + k8 * 8);
        *(uint4*)&qs[i][k8 * 8] = v;
    }

    for (int j0 = 0; j0 < SEQ; j0 += 64) {
        // stage k tile
        {
            int j = tid >> 3, k8 = tid & 7;
            uint4 v = *(const uint4*)(kb + ((size_t)(b * SEQ + j0 + j) * DIM) + h * DH + k8 * 8);
            *(uint4*)&kt[j][k8 * 8] = v;
        }
        // stage position band: t_abs = t0 + t, t in [0,128)
        const int t0 = j0 - i0 + 320;
        for (int p = 0; p < 2; ++p) {
            int e = tid + p * 512;
            int t = e >> 3, k8 = e & 7;
            int row = t0 + t; if (row > NPOS - 1) row = NPOS - 1;
            uint4 v1 = *(const uint4*)(Kpb + (size_t)row * DIM + h * DH + k8 * 8);
            *(uint4*)&kps[t][k8 * 8] = v1;
            uint4 v2 = *(const uint4*)(Qpb + (size_t)row * DIM + h * DH + k8 * 8);
            *(uint4*)&qps[t][k8 * 8] = v2;
        }
        __syncthreads();

        // c2c: q @ k^T -> cc[64][64]; 16 tiles, 2 per wave
#pragma unroll
        for (int s = 0; s < 2; ++s) {
            int idx = wave * 2 + s;
            int tr = idx >> 2, tc = idx & 3;
            floatx4 acc = {};
#pragma unroll
            for (int kk = 0; kk < 64; kk += 32) {
                short8 a = *(const short8*)&qs[tr * 16 + (lane & 15)][kk + (lane >> 4) * 8];
                short8 bb = *(const short8*)&kt[tc * 16 + (lane & 15)][kk + (lane >> 4) * 8];
                acc = __builtin_amdgcn_mfma_f32_16x16x32_bf16(a, bb, acc, 0, 0, 0);
            }
            int col = tc * 16 + (lane & 15);
#pragma unroll
            for (int r = 0; r < 4; ++r) cc[tr * 16 + (lane >> 4) * 4 + r][col] = acc[r];
        }
        // Dq: q @ kps^T -> dq[64 i][128 t]; 32 tiles, 4 per wave
#pragma unroll
        for (int s = 0; s < 4; ++s) {
            int idx = wave * 4 + s;
            int tr = idx >> 3, tc = idx & 7;
            floatx4 acc = {};
#pragma unroll
            for (int kk = 0; kk < 64; kk += 32) {
                short8 a = *(const short8*)&qs[tr * 16 + (lane & 15)][kk + (lane >> 4) * 8];
                short8 bb = *(const short8*)&kps[tc * 16 + (lane & 15)][kk + (lane >> 4) * 8];
                acc = __builtin_amdgcn_mfma_f32_16x16x32_bf16(a, bb, acc, 0, 0, 0);
            }
            int col = tc * 16 + (lane & 15);
#pragma unroll
            for (int r = 0; r < 4; ++r) dq[tr * 16 + (lane >> 4) * 4 + r][col] = acc[r];
        }
        // Dk: qps @ k^T -> dk[128 t][64 j]; 32 tiles, 4 per wave
#pragma unroll
        for (int s = 0; s < 4; ++s) {
            int idx = wave * 4 + s;
            int tr = idx >> 2, tc = idx & 3;
            floatx4 acc = {};
#pragma unroll
            for (int kk = 0; kk < 64; kk += 32) {
                short8 a = *(const short8*)&qps[tr * 16 + (lane & 15)][kk + (lane >> 4) * 8];
                short8 bb = *(const short8*)&kt[tc * 16 + (lane & 15)][kk + (lane >> 4) * 8];
                acc = __builtin_amdgcn_mfma_f32_16x16x32_bf16(a, bb, acc, 0, 0, 0);
            }
            int col = tc * 16 + (lane & 15);
#pragma unroll
            for (int r = 0; r < 4; ++r) dk[tr * 16 + (lane >> 4) * 4 + r][col] = acc[r];
        }
        __syncthreads();

        // combine: s[i][j] = (cc + dq[i][j-i+63] + dk[j-i+63][j]) * scale
        {
            int ci = tid >> 3, jb = (tid & 7) * 8;
            size_t rowbase = ((size_t)(b * NH + h) * SEQ + i0 + ci) * SEQ + j0;
#pragma unroll
            for (int jj = 0; jj < 8; ++jj) {
                int j = jb + jj;
                int t = j - ci + 63;
                float s = (cc[ci][j] + dq[ci][t] + dk[t][j]) * 0.125f;
                scores[rowbase + j] = s;
            }
        }
        __syncthreads();
    }
}

// ---------- softmax: in-place fp32, one wave per row of 384 ---------------
__global__ __launch_bounds__(256) void softmax_kernel(float* __restrict__ scores) {
    const int tid = threadIdx.x;
    const int lane = tid & 63, wave = tid >> 6;
    const size_t row = (size_t)blockIdx.x * 4 + wave;
    float* base = scores + row * SEQ;
    float v[6];
#pragma unroll
    for (int c = 0; c < 6; ++c) v[c] = base[c * 64 + lane];
    float m = v[0];
#pragma unroll
    for (int c = 1; c < 6; ++c) m = fmaxf(m, v[c]);
#pragma unroll
    for (int off = 32; off >= 1; off >>= 1) m = fmaxf(m, __shfl_xor(m, off));
    float s = 0.f;
#pragma unroll
    for (int c = 0; c < 6; ++c) { v[c] = __expf(v[c] - m); s += v[c]; }
#pragma unroll
    for (int off = 32; off >= 1; off >>= 1) s += __shfl_xor(s, off);
    float inv = 1.f / s;
#pragma unroll
    for (int c = 0; c < 6; ++c) base[c * 64 + lane] = v[c] * inv;
}

// ---------- PV: out[b,i,h*64+d] = sum_j P[b,h,i,j] v[b,j,h*64+d] ----------
// grid (S/64, NH, BATCH), 256 threads (4 waves). P is fp32 (converted here).
__global__ __launch_bounds__(256) void pv_kernel(
    const float* __restrict__ P, const ushort* __restrict__ vb,
    ushort* __restrict__ aob)
{
    __shared__ ushort ps[64][72];
    __shared__ ushort vs[64][72];
    const int tid = threadIdx.x;
    const int lane = tid & 63, wave = tid >> 6;
    const int i0 = blockIdx.x * 64;
    const int h = blockIdx.y;
    const int b = blockIdx.z;
    floatx4 acc[4] = {};
    for (int j0 = 0; j0 < SEQ; j0 += 64) {
        for (int p = 0; p < 2; ++p) {
            int e = tid + p * 256;
            int i = e >> 3, k8 = e & 7;
            const float4* src = (const float4*)(P + ((size_t)(b * NH + h) * SEQ + i0 + i) * SEQ + j0 + k8 * 8);
            float4 f0 = src[0], f1 = src[1];
            ushort tmp[8] = {f2bf(f0.x), f2bf(f0.y), f2bf(f0.z), f2bf(f0.w),
                             f2bf(f1.x), f2bf(f1.y), f2bf(f1.z), f2bf(f1.w)};
            *(uint4*)&ps[i][k8 * 8] = *(uint4*)tmp;
        }
        for (int p = 0; p < 2; ++p) {
            int e = tid + p * 256;
            int j = e >> 3, d8 = e & 7;
            uint4 w = *(const uint4*)(vb + ((size_t)(b * SEQ + j0 + j) * DIM) + h * DH + d8 * 8);
            const ushort* pw = (const ushort*)&w;
#pragma unroll
            for (int dd = 0; dd < 8; ++dd) vs[d8 * 8 + dd][j] = pw[dd];
        }
        __syncthreads();
#pragma unroll
        for (int s = 0; s < 4; ++s) {
            int idx = wave * 4 + s;
            int tr = idx >> 2, tc = idx & 3;
#pragma unroll
            for (int kk = 0; kk < 64; kk += 32) {
                short8 a = *(const short8*)&ps[tr * 16 + (lane & 15)][kk + (lane >> 4) * 8];
                short8 bb = *(const short8*)&vs[tc * 16 + (lane & 15)][kk + (lane >> 4) * 8];
                acc[s] = __builtin_amdgcn_mfma_f32_16x16x32_bf16(a, bb, acc[s], 0, 0, 0);
            }
        }
        __syncthreads();
    }
#pragma unroll
    for (int s = 0; s < 4; ++s) {
        int idx = wave * 4 + s;
        int tr = idx >> 2, tc = idx & 3;
        int col = tc * 16 + (lane & 15);
#pragma unroll
        for (int r = 0; r < 4; ++r) {
            int row = tr * 16 + (lane >> 4) * 4 + r;
            aob[((size_t)(b * SEQ) + i0 + row) * DIM + h * DH + col] = f2bf(acc[s][r]);
        }
    }
}

extern "C" void kernel_launch(void* const* d_in, const int* in_sizes, int n_in,
                              void* d_out, int out_size, void* d_ws, size_t ws_size,
                              hipStream_t stream) {
    const float* x   = (const float*)d_in[0];
    const float* rpe = (const float*)d_in[1];
    const float* Wq  = (const float*)d_in[2];
    const float* bq  = (const float*)d_in[3];
    const float* Wk  = (const float*)d_in[4];
    const float* bk  = (const float*)d_in[5];
    const float* Wv  = (const float*)d_in[6];
    const float* bv  = (const float*)d_in[7];
    const float* qbias = (const float*)d_in[8];
    const float* vbias = (const float*)d_in[9];
    const float* Wpk = (const float*)d_in[10];
    const float* Wpq = (const float*)d_in[11];
    const float* Wo  = (const float*)d_in[12];
    const float* bo  = (const float*)d_in[13];
    float* out = (float*)d_out;

    // workspace layout
    char* ws = (char*)d_ws;
    float* scores = (float*)ws;                       // 8*12*384*384 fp32 = 56.6MB
    ws += (size_t)BATCH * NH * SEQ * SEQ * 4;
    ushort* xb = (ushort*)ws;  ws += (size_t)NTOK * DIM * 2;   // reused as aob
    ushort* qbuf = (ushort*)ws; ws += (size_t)NTOK * DIM * 2;
    ushort* kbuf = (ushort*)ws; ws += (size_t)NTOK * DIM * 2;
    ushort* vbuf = (ushort*)ws; ws += (size_t)NTOK * DIM * 2;
    ushort* rpeb = (ushort*)ws; ws += (size_t)NPOS * DIM * 2;
    ushort* Kpb = (ushort*)ws;  ws += (size_t)NPOS * DIM * 2;
    ushort* Qpb = (ushort*)ws;  ws += (size_t)NPOS * DIM * 2;
    ushort* Wt[6];
    for (int i = 0; i < 6; ++i) { Wt[i] = (ushort*)ws; ws += (size_t)DIM * DIM * 2; }
    // Wt order: Wq, Wk, Wv, Wpk, Wpq, Wo

    dim3 b256(256);
    // converts
    {
        int n4 = NTOK * DIM / 4;
        cvt_rows<<<(n4 + 255) / 256, b256, 0, stream>>>(x, xb, n4);
        int n4p = NPOS * DIM / 4;
        cvt_rows<<<(n4p + 255) / 256, b256, 0, stream>>>(rpe + (size_t)POS_OFF * DIM, rpeb, n4p);
        dim3 gt(DIM / 64, DIM / 64);
        const float* Wsrc[6] = {Wq, Wk, Wv, Wpk, Wpq, Wo};
        for (int i = 0; i < 6; ++i)
            cvt_transpose<<<gt, b256, 0, stream>>>(Wsrc[i], Wt[i]);
    }
    // projections
    dim3 gproj(DIM / 64, NTOK / 64);
    gemm_bf16<<<gproj, b256, 0, stream>>>(xb, Wt[0], bq, qbias, nullptr, qbuf, NTOK, DIM, DIM);
    gemm_bf16<<<gproj, b256, 0, stream>>>(xb, Wt[1], bk, nullptr, nullptr, kbuf, NTOK, DIM, DIM);
    gemm_bf16<<<gproj, b256, 0, stream>>>(xb, Wt[2], bv, vbias, nullptr, vbuf, NTOK, DIM, DIM);
    dim3 gpos(DIM / 64, (NPOS + 63) / 64);
    gemm_bf16<<<gpos, b256, 0, stream>>>(rpeb, Wt[3], nullptr, nullptr, nullptr, Kpb, NPOS, DIM, DIM);
    gemm_bf16<<<gpos, b256, 0, stream>>>(rpeb, Wt[4], nullptr, nullptr, nullptr, Qpb, NPOS, DIM, DIM);
    // scores
    dim3 gsc(SEQ / 64, NH, BATCH);
    score_kernel<<<gsc, dim3(512), 0, stream>>>(qbuf, kbuf, Kpb, Qpb, scores);
    // softmax (in-place fp32)
    softmax_kernel<<<(BATCH * NH * SEQ) / 4, b256, 0, stream>>>(scores);
    // PV -> aob (reuse xb region)
    ushort* aob = xb;
    pv_kernel<<<gsc, b256, 0, stream>>>(scores, vbuf, aob);
    // output projection (fp32 out + bias)
    gemm_bf16<<<gproj, b256, 0, stream>>>(aob, Wt[5], bo, nullptr, out, nullptr, NTOK, DIM, DIM);
}